// Round 1
// baseline (807.668 us; speedup 1.0000x reference)
//
#include <hip/hip_runtime.h>
#include <hip/hip_fp16.h>

#define E_EDGES 102400
#define N_NODES 100000
#define G_GRAPHS 64
#define D_EDGE 256
#define D_NODE 256
#define D_GLOB 128
#define KNB 4
#define D_IN 1408   // 256 + 4*256 + 128
#define H1D 512
#define H2D 512
#define H3D 256
#define LN_EPS 1e-3f

typedef _Float16 half8 __attribute__((ext_vector_type(8)));
typedef _Float16 half4v __attribute__((ext_vector_type(4)));
typedef float f32x4 __attribute__((ext_vector_type(4)));

// ---------------- prep kernels ----------------

__global__ void k_prefix(const int* __restrict__ num, int* __restrict__ prefix) {
    if (threadIdx.x == 0) {
        int acc = 0;
        prefix[0] = 0;
        for (int g = 0; g < G_GRAPHS; ++g) { acc += num[g]; prefix[g + 1] = acc; }
    }
}

__global__ void k_gid(const int* __restrict__ prefix, int* __restrict__ gid) {
    int e = blockIdx.x * blockDim.x + threadIdx.x;
    if (e >= E_EDGES) return;
    int lo = 0, hi = G_GRAPHS;
    while (hi - lo > 1) {
        int mid = (lo + hi) >> 1;
        if (e >= prefix[mid]) lo = mid; else hi = mid;
    }
    gid[e] = lo;
}

// dst[n*Ks + k] = (f16) src[k*Ns + n]   (transpose + fp32->f16)
__global__ void k_transpose(const float* __restrict__ src, _Float16* __restrict__ dst,
                            int Ks, int Ns) {
    long total = (long)Ks * Ns;
    for (long idx = (long)blockIdx.x * blockDim.x + threadIdx.x; idx < total;
         idx += (long)gridDim.x * blockDim.x) {
        int n = (int)(idx / Ks);
        int k = (int)(idx - (long)n * Ks);
        dst[idx] = (_Float16)src[(long)k * Ns + n];
    }
}

// ---------------- GEMM1: gather-fused  [E,1408] x W1t -> relu -> h1[E,512] f16 ----------------
// BM=128 BN=128 BK=64, 256 thr = 4 waves (2x2), wave tile 64x64, mfma 16x16x32 f16

__global__ __launch_bounds__(256) void k_gemm1(
    const float* __restrict__ feat, const float* __restrict__ nodes,
    const float* __restrict__ gfeat, const int* __restrict__ ind,
    const int* __restrict__ gid, const _Float16* __restrict__ Wt,
    const float* __restrict__ bias, _Float16* __restrict__ out) {
    __shared__ __align__(16) _Float16 As[128][72];
    __shared__ __align__(16) _Float16 Bs[128][72];
    const int t = threadIdx.x;
    const int bm = blockIdx.x, bn = blockIdx.y;
    const int w = t >> 6, lane = t & 63;
    const int wr = w >> 1, wc = w & 1, lr = lane & 15, lk = lane >> 4;

    f32x4 acc[4][4];
#pragma unroll
    for (int m = 0; m < 4; m++)
#pragma unroll
        for (int n = 0; n < 4; n++) acc[m][n] = (f32x4)0.f;

    const int r = t >> 1;            // A staging: 2 threads per row
    const int e = bm * 128 + r;
    const int cbase = (t & 1) * 32;  // 32 cols each
    const int n0 = bn * 128;

    for (int kt = 0; kt < 22; ++kt) {
        const int k0 = kt * 64;
        __syncthreads();
        // ---- stage A: gather + cvt ----
        const float* src;
        long base;
        if (kt < 4) {
            src = feat; base = (long)e * D_EDGE + k0;
        } else if (kt < 20) {
            int j = (kt - 4) >> 2;
            int c0 = ((kt - 4) & 3) * 64;
            src = nodes; base = (long)ind[e * KNB + j] * D_NODE + c0;
        } else {
            src = gfeat; base = (long)gid[e] * D_GLOB + (kt - 20) * 64;
        }
#pragma unroll
        for (int i = 0; i < 8; i++) {
            float4 f = *reinterpret_cast<const float4*>(src + base + cbase + i * 4);
            half4v h;
            h.x = (_Float16)f.x; h.y = (_Float16)f.y;
            h.z = (_Float16)f.z; h.w = (_Float16)f.w;
            *reinterpret_cast<half4v*>(&As[r][cbase + i * 4]) = h;
        }
        // ---- stage B: Wt rows (= output cols), already f16 ----
#pragma unroll
        for (int i = 0; i < 4; i++) {
            int idx = t + 256 * i;
            int n = idx >> 3, ch = idx & 7;
            half8 v = *reinterpret_cast<const half8*>(Wt + (long)(n0 + n) * D_IN + k0 + ch * 8);
            *reinterpret_cast<half8*>(&Bs[n][ch * 8]) = v;
        }
        __syncthreads();
#pragma unroll
        for (int kk = 0; kk < 2; kk++) {
            half8 a[4], b[4];
#pragma unroll
            for (int m = 0; m < 4; m++)
                a[m] = *reinterpret_cast<half8*>(&As[wr * 64 + m * 16 + lr][kk * 32 + lk * 8]);
#pragma unroll
            for (int n = 0; n < 4; n++)
                b[n] = *reinterpret_cast<half8*>(&Bs[wc * 64 + n * 16 + lr][kk * 32 + lk * 8]);
#pragma unroll
            for (int m = 0; m < 4; m++)
#pragma unroll
                for (int n = 0; n < 4; n++)
                    acc[m][n] = __builtin_amdgcn_mfma_f32_16x16x32_f16(a[m], b[n], acc[m][n], 0, 0, 0);
        }
    }
    // ---- epilogue: relu(acc + bias) -> f16 ----
#pragma unroll
    for (int n = 0; n < 4; n++) {
        int col = n0 + wc * 64 + n * 16 + lr;
        float bv = bias[col];
#pragma unroll
        for (int m = 0; m < 4; m++) {
            int rbase = bm * 128 + wr * 64 + m * 16 + lk * 4;
#pragma unroll
            for (int q = 0; q < 4; q++) {
                float v = acc[m][n][q] + bv;
                v = v > 0.f ? v : 0.f;
                out[(long)(rbase + q) * H1D + col] = (_Float16)v;
            }
        }
    }
}

// ---------------- GEMM2: h1[E,512] x W2t -> relu -> h2[E,512] f16 ----------------

__global__ __launch_bounds__(256) void k_gemm2(
    const _Float16* __restrict__ A, const _Float16* __restrict__ Wt,
    const float* __restrict__ bias, _Float16* __restrict__ out) {
    __shared__ __align__(16) _Float16 As[128][72];
    __shared__ __align__(16) _Float16 Bs[128][72];
    const int t = threadIdx.x;
    const int bm = blockIdx.x, bn = blockIdx.y;
    const int w = t >> 6, lane = t & 63;
    const int wr = w >> 1, wc = w & 1, lr = lane & 15, lk = lane >> 4;
    const int n0 = bn * 128;

    f32x4 acc[4][4];
#pragma unroll
    for (int m = 0; m < 4; m++)
#pragma unroll
        for (int n = 0; n < 4; n++) acc[m][n] = (f32x4)0.f;

    for (int kt = 0; kt < 8; ++kt) {
        const int k0 = kt * 64;
        __syncthreads();
#pragma unroll
        for (int i = 0; i < 4; i++) {
            int idx = t + 256 * i;
            int r = idx >> 3, ch = idx & 7;
            half8 v = *reinterpret_cast<const half8*>(A + (long)(bm * 128 + r) * H1D + k0 + ch * 8);
            *reinterpret_cast<half8*>(&As[r][ch * 8]) = v;
        }
#pragma unroll
        for (int i = 0; i < 4; i++) {
            int idx = t + 256 * i;
            int n = idx >> 3, ch = idx & 7;
            half8 v = *reinterpret_cast<const half8*>(Wt + (long)(n0 + n) * H1D + k0 + ch * 8);
            *reinterpret_cast<half8*>(&Bs[n][ch * 8]) = v;
        }
        __syncthreads();
#pragma unroll
        for (int kk = 0; kk < 2; kk++) {
            half8 a[4], b[4];
#pragma unroll
            for (int m = 0; m < 4; m++)
                a[m] = *reinterpret_cast<half8*>(&As[wr * 64 + m * 16 + lr][kk * 32 + lk * 8]);
#pragma unroll
            for (int n = 0; n < 4; n++)
                b[n] = *reinterpret_cast<half8*>(&Bs[wc * 64 + n * 16 + lr][kk * 32 + lk * 8]);
#pragma unroll
            for (int m = 0; m < 4; m++)
#pragma unroll
                for (int n = 0; n < 4; n++)
                    acc[m][n] = __builtin_amdgcn_mfma_f32_16x16x32_f16(a[m], b[n], acc[m][n], 0, 0, 0);
        }
    }
#pragma unroll
    for (int n = 0; n < 4; n++) {
        int col = n0 + wc * 64 + n * 16 + lr;
        float bv = bias[col];
#pragma unroll
        for (int m = 0; m < 4; m++) {
            int rbase = bm * 128 + wr * 64 + m * 16 + lk * 4;
#pragma unroll
            for (int q = 0; q < 4; q++) {
                float v = acc[m][n][q] + bv;
                v = v > 0.f ? v : 0.f;
                out[(long)(rbase + q) * H2D + col] = (_Float16)v;
            }
        }
    }
}

// ---------------- GEMM3 + sigmoid + LayerNorm: h2[E,512] x W3t -> out[E,256] f32 ----------------
// BM=128 BN=256 (full width so LN lives in-block), 512 thr = 8 waves (2x4)

__global__ __launch_bounds__(512) void k_gemm3_ln(
    const _Float16* __restrict__ A, const _Float16* __restrict__ Wt,
    const float* __restrict__ bias, const float* __restrict__ gamma,
    const float* __restrict__ beta, float* __restrict__ out) {
    __shared__ __align__(16) _Float16 As[128][72];
    __shared__ __align__(16) _Float16 Bs[256][72];
    __shared__ float red1[128][4];
    __shared__ float red2[128][4];
    __shared__ float mvmu[128];
    __shared__ float mvrs[128];
    const int t = threadIdx.x;
    const int bm = blockIdx.x;
    const int w = t >> 6, lane = t & 63;
    const int wr = w >> 2, wc = w & 3, lr = lane & 15, lk = lane >> 4;

    f32x4 acc[4][4];
#pragma unroll
    for (int m = 0; m < 4; m++)
#pragma unroll
        for (int n = 0; n < 4; n++) acc[m][n] = (f32x4)0.f;

    for (int kt = 0; kt < 8; ++kt) {
        const int k0 = kt * 64;
        __syncthreads();
#pragma unroll
        for (int i = 0; i < 2; i++) {
            int idx = t + 512 * i;
            int r = idx >> 3, ch = idx & 7;
            half8 v = *reinterpret_cast<const half8*>(A + (long)(bm * 128 + r) * H2D + k0 + ch * 8);
            *reinterpret_cast<half8*>(&As[r][ch * 8]) = v;
        }
#pragma unroll
        for (int i = 0; i < 4; i++) {
            int idx = t + 512 * i;
            int n = idx >> 3, ch = idx & 7;
            half8 v = *reinterpret_cast<const half8*>(Wt + (long)n * H2D + k0 + ch * 8);
            *reinterpret_cast<half8*>(&Bs[n][ch * 8]) = v;
        }
        __syncthreads();
#pragma unroll
        for (int kk = 0; kk < 2; kk++) {
            half8 a[4], b[4];
#pragma unroll
            for (int m = 0; m < 4; m++)
                a[m] = *reinterpret_cast<half8*>(&As[wr * 64 + m * 16 + lr][kk * 32 + lk * 8]);
#pragma unroll
            for (int n = 0; n < 4; n++)
                b[n] = *reinterpret_cast<half8*>(&Bs[wc * 64 + n * 16 + lr][kk * 32 + lk * 8]);
#pragma unroll
            for (int m = 0; m < 4; m++)
#pragma unroll
                for (int n = 0; n < 4; n++)
                    acc[m][n] = __builtin_amdgcn_mfma_f32_16x16x32_f16(a[m], b[n], acc[m][n], 0, 0, 0);
        }
    }

    // bias + sigmoid (in fp32, h3 never hits HBM)
#pragma unroll
    for (int n = 0; n < 4; n++) {
        int col = wc * 64 + n * 16 + lr;
        float bv = bias[col];
#pragma unroll
        for (int m = 0; m < 4; m++)
#pragma unroll
            for (int q = 0; q < 4; q++) {
                float x = acc[m][n][q] + bv;
                acc[m][n][q] = 1.f / (1.f + __expf(-x));
            }
    }

    // LayerNorm over 256 cols: per-lane partials -> 16-lane butterfly -> cross-wave LDS
#pragma unroll
    for (int m = 0; m < 4; m++)
#pragma unroll
        for (int q = 0; q < 4; q++) {
            float s1 = 0.f, s2 = 0.f;
#pragma unroll
            for (int n = 0; n < 4; n++) {
                float x = acc[m][n][q];
                s1 += x; s2 += x * x;
            }
            s1 += __shfl_xor(s1, 1); s2 += __shfl_xor(s2, 1);
            s1 += __shfl_xor(s1, 2); s2 += __shfl_xor(s2, 2);
            s1 += __shfl_xor(s1, 4); s2 += __shfl_xor(s2, 4);
            s1 += __shfl_xor(s1, 8); s2 += __shfl_xor(s2, 8);
            if (lr == 0) {
                int row = wr * 64 + m * 16 + lk * 4 + q;
                red1[row][wc] = s1;
                red2[row][wc] = s2;
            }
        }
    __syncthreads();
    if (t < 128) {
        float s = red1[t][0] + red1[t][1] + red1[t][2] + red1[t][3];
        float ss = red2[t][0] + red2[t][1] + red2[t][2] + red2[t][3];
        float mu = s * (1.f / H3D);
        float var = ss * (1.f / H3D) - mu * mu;
        mvmu[t] = mu;
        mvrs[t] = rsqrtf(var + LN_EPS);
    }
    __syncthreads();
#pragma unroll
    for (int m = 0; m < 4; m++)
#pragma unroll
        for (int q = 0; q < 4; q++) {
            int row = wr * 64 + m * 16 + lk * 4 + q;
            float mu = mvmu[row], rs = mvrs[row];
#pragma unroll
            for (int n = 0; n < 4; n++) {
                int col = wc * 64 + n * 16 + lr;
                out[(long)(bm * 128 + row) * H3D + col] =
                    gamma[col] * (acc[m][n][q] - mu) * rs + beta[col];
            }
        }
}

// ---------------- launch ----------------

extern "C" void kernel_launch(void* const* d_in, const int* in_sizes, int n_in,
                              void* d_out, int out_size, void* d_ws, size_t ws_size,
                              hipStream_t stream) {
    const float* feat  = (const float*)d_in[0];
    const float* nodes = (const float*)d_in[1];
    const float* gfeat = (const float*)d_in[2];
    const int*   ind   = (const int*)d_in[3];
    const int*   num   = (const int*)d_in[4];
    const float* W1    = (const float*)d_in[5];
    const float* b1    = (const float*)d_in[6];
    const float* W2    = (const float*)d_in[7];
    const float* b2    = (const float*)d_in[8];
    const float* W3    = (const float*)d_in[9];
    const float* b3    = (const float*)d_in[10];
    const float* gamma = (const float*)d_in[11];
    const float* beta  = (const float*)d_in[12];
    float* out = (float*)d_out;

    char* ws = (char*)d_ws;
    size_t off = 0;
    auto alloc = [&](size_t bytes) {
        size_t o = off;
        off += (bytes + 255) & ~(size_t)255;
        return o;
    };
    int* prefix    = (int*)(ws + alloc((G_GRAPHS + 1) * sizeof(int)));
    int* gid       = (int*)(ws + alloc((size_t)E_EDGES * sizeof(int)));
    _Float16* W1t  = (_Float16*)(ws + alloc((size_t)H1D * D_IN * 2));
    _Float16* W2t  = (_Float16*)(ws + alloc((size_t)H2D * H1D * 2));
    _Float16* W3t  = (_Float16*)(ws + alloc((size_t)H3D * H2D * 2));
    _Float16* h1   = (_Float16*)(ws + alloc((size_t)E_EDGES * H1D * 2));
    _Float16* h2   = (_Float16*)(ws + alloc((size_t)E_EDGES * H2D * 2));
    (void)ws_size; (void)in_sizes; (void)n_in; (void)out_size;

    k_prefix<<<1, 64, 0, stream>>>(num, prefix);
    k_gid<<<(E_EDGES + 255) / 256, 256, 0, stream>>>(prefix, gid);
    k_transpose<<<1024, 256, 0, stream>>>(W1, W1t, D_IN, H1D);
    k_transpose<<<512, 256, 0, stream>>>(W2, W2t, H1D, H2D);
    k_transpose<<<256, 256, 0, stream>>>(W3, W3t, H2D, H3D);
    k_gemm1<<<dim3(E_EDGES / 128, H1D / 128), 256, 0, stream>>>(feat, nodes, gfeat, ind, gid, W1t, b1, h1);
    k_gemm2<<<dim3(E_EDGES / 128, H2D / 128), 256, 0, stream>>>(h1, W2t, b2, h2);
    k_gemm3_ln<<<E_EDGES / 128, 512, 0, stream>>>(h2, W3t, b3, gamma, beta, out);
}